// Round 5
// baseline (334.036 us; speedup 1.0000x reference)
//
#include <hip/hip_runtime.h>

#define NBATCH 4
#define NS 2048
#define ND 1024
#define NH 8
#define HD 128
#define NFF 512
#define NE 8
#define NT 65536       /* B*S*H tokens */
#define NBS 8192       /* B*S rows */
#define MU_F 0.7f
#define LN_EPS_F 1e-5f

typedef __attribute__((ext_vector_type(4))) float f32x4;
typedef __attribute__((ext_vector_type(2))) double f64x2;
typedef __attribute__((ext_vector_type(8))) _Float16 f16x8;
typedef __attribute__((ext_vector_type(4))) _Float16 f16x4;
typedef __attribute__((ext_vector_type(2))) _Float16 f16x2;

__device__ __forceinline__ void gload_lds16(const void* g, void* l) {
  __builtin_amdgcn_global_load_lds(
      (const __attribute__((address_space(1))) unsigned int*)g,
      (__attribute__((address_space(3))) unsigned int*)l, 16, 0, 0);
}

// cnt is strided: cnt[e*64] so the 8 counters live in different cache lines/TCC channels
__global__ void zero_cnt_kernel(int* cnt) {
  cnt[threadIdx.x] = 0;
}

// plain fp32 -> fp16 convert, 4 elems/thread
__global__ void cvt_f16_kernel(const float* __restrict__ in, _Float16* __restrict__ out, int n4) {
  int i = blockIdx.x * blockDim.x + threadIdx.x;
  if (i >= n4) return;
  float4 v = ((const float4*)in)[i];
  f16x4 h = { (_Float16)v.x, (_Float16)v.y, (_Float16)v.z, (_Float16)v.w };
  *(f16x4*)(out + (size_t)i * 4) = h;
}

// batched transpose + convert: in [batch][R][C] f32 -> out [batch][C][R] f16
// R, C multiples of 32. block (32,8), grid (C/32, R/32, batch)
__global__ void tr_cvt_kernel(const float* __restrict__ in, _Float16* __restrict__ out, int R, int C) {
  __shared__ float tile[32][33];
  int b = blockIdx.z;
  const float* inp = in + (size_t)b * R * C;
  _Float16* outp = out + (size_t)b * R * C;
  int c = blockIdx.x * 32 + threadIdx.x;
  int r0 = blockIdx.y * 32;
  #pragma unroll
  for (int i = 0; i < 4; i++) {
    int r = r0 + threadIdx.y + i * 8;
    tile[threadIdx.y + i * 8][threadIdx.x] = inp[(size_t)r * C + c];
  }
  __syncthreads();
  int rr = r0 + threadIdx.x;
  #pragma unroll
  for (int i = 0; i < 4; i++) {
    int cc = blockIdx.x * 32 + threadIdx.y + i * 8;
    outp[(size_t)cc * R + rr] = (_Float16)tile[threadIdx.x][threadIdx.y + i * 8];
  }
}

// G[d][o] (o = h*8+e) = sum_j split_W[d][h*128+j] * gate_W[j][e]  (fp64)
// gbias[o] = split_b[h*128:] . gate_W[:,e] + gate_b[e]
__global__ void build_G_kernel(const float* __restrict__ split_W, const float* __restrict__ split_b,
                               const float* __restrict__ gate_W, const float* __restrict__ gate_b,
                               double* __restrict__ G, double* __restrict__ gbias) {
  int idx = blockIdx.x * 256 + threadIdx.x;   // 65536 total
  int d = idx >> 6, o = idx & 63, h = o >> 3, e = o & 7;
  double acc = 0.0;
  for (int j = 0; j < 128; j++)
    acc += (double)split_W[(size_t)d * ND + h * 128 + j] * (double)gate_W[j * 8 + e];
  G[idx] = acc;
  if (idx < 64) {
    double bacc = 0.0;
    for (int j = 0; j < 128; j++)
      bacc += (double)split_b[h * 128 + j] * (double)gate_W[j * 8 + e];
    gbias[idx] = bacc + (double)gate_b[e];
  }
}

// fp64 logits = x @ G + gbias, top-2 per (row,h), softmax, per-expert lists.
// v4: LDS fp64 mini-GEMM (conflict-free Gsx[kp][col] f64x2 layout) +
// hierarchical atomics (LDS counts -> 8 strided global atomics/block).
__global__ __launch_bounds__(256) void gate_kernel(const float* __restrict__ x,
    const double* __restrict__ G, const double* __restrict__ gbias,
    float* __restrict__ tkw, int* __restrict__ lists, int* __restrict__ cnt) {
  __shared__ f64x2 Gsx[32 * 64];     // 32 KB, [kp][col]
  __shared__ double xsd[16][66];     // 8.25 KB
  __shared__ double lg[16 * 64];     // 8 KB
  __shared__ int lcnt[8];
  __shared__ int lbase[8];
  int tid = threadIdx.x, lane = tid & 63, w = tid >> 6;
  int bs0 = blockIdx.x * 16;
  double acc[4];
  #pragma unroll
  for (int r = 0; r < 4; r++) acc[r] = 0.0;
  int xrow = tid >> 4, xc4 = tid & 15;
  const double* xr = &xsd[0][0] + (w * 4) * 66;
  if (tid < 8) lcnt[tid] = 0;

  for (int ch = 0; ch < 16; ch++) {
    __syncthreads();           // previous chunk's reads complete before overwrite
    float4 xv4 = *(const float4*)(x + (size_t)(bs0 + xrow) * ND + ch * 64 + xc4 * 4);
    f64x2 xa = { (double)xv4.x, (double)xv4.y };
    f64x2 xb = { (double)xv4.z, (double)xv4.w };
    *(f64x2*)&xsd[xrow][xc4 * 4]     = xa;
    *(f64x2*)&xsd[xrow][xc4 * 4 + 2] = xb;
    #pragma unroll
    for (int i = 0; i < 8; i++) {
      int idx = i * 256 + tid, kp = idx >> 6, c = idx & 63;
      const double* gp = G + (size_t)(ch * 64 + kp * 2) * 64 + c;
      f64x2 gv = { gp[0], gp[64] };
      Gsx[idx] = gv;
    }
    __syncthreads();
    #pragma unroll 4
    for (int kp = 0; kp < 32; kp++) {
      f64x2 g = Gsx[kp * 64 + lane];       // contiguous 16B/lane: conflict-free
      #pragma unroll
      for (int r = 0; r < 4; r++) {
        f64x2 xv = *(const f64x2*)(xr + r * 66 + kp * 2);   // broadcast
        acc[r] += xv.x * g.x;
        acc[r] += xv.y * g.y;
      }
    }
  }
  double gb = gbias[lane];
  #pragma unroll
  for (int r = 0; r < 4; r++)
    lg[(w * 4 + r) * 64 + lane] = acc[r] + gb;
  __syncthreads();

  int i1 = 0, i2 = 0, token = 0, p1 = 0, p2 = 0;
  if (tid < 128) {
    int row = tid >> 3, h = tid & 7;
    const double* L = lg + row * 64 + h * 8;
    double v1 = L[0];
    #pragma unroll
    for (int e2 = 1; e2 < 8; e2++) if (L[e2] > v1) { v1 = L[e2]; i1 = e2; }
    i2 = -1; double v2 = -1e300;
    #pragma unroll
    for (int e2 = 0; e2 < 8; e2++) if (e2 != i1 && L[e2] > v2) { v2 = L[e2]; i2 = e2; }
    float ex = expf((float)(v2 - v1));        // <= 1
    float den = 1.f + ex;
    float g1 = 1.f / den, g2 = ex / den;
    token = (bs0 + row) * 8 + h;
    tkw[token * 2]     = g1;
    tkw[token * 2 + 1] = g2;
    p1 = atomicAdd(&lcnt[i1], 1);             // LDS atomics: cheap
    p2 = atomicAdd(&lcnt[i2], 1);
  }
  __syncthreads();
  if (tid < 8) lbase[tid] = atomicAdd(cnt + tid * 64, lcnt[tid]);   // 8 global atomics/block
  __syncthreads();
  if (tid < 128) {
    lists[(size_t)i1 * NT + lbase[i1] + p1] = token * 2;
    lists[(size_t)i2 * NT + lbase[i2] + p2] = token * 2 + 1;
  }
}

// C[M][N] = A[M][K] @ Bt[N][K]^T + bias; fp16 inputs, fp32 acc.
// 128x128 tile, BK=32, 4 waves (2x2 of 64x64), global_load_lds width 16.
__global__ __launch_bounds__(256) void gemm_f16_kernel(
    const _Float16* __restrict__ A, const _Float16* __restrict__ Bt,
    const float* __restrict__ bias, float* __restrict__ Cf, _Float16* __restrict__ Ch,
    int M, int N, int Kd) {
  __shared__ _Float16 As[128 * 32];
  __shared__ _Float16 Bs[128 * 32];
  int tid = threadIdx.x, lane = tid & 63, w = tid >> 6;
  int wr = w >> 1, wc = w & 1;
  int m0 = blockIdx.y * 128, n0 = blockIdx.x * 128;
  f32x4 acc[4][4];
  #pragma unroll
  for (int i = 0; i < 4; i++)
    #pragma unroll
    for (int j = 0; j < 4; j++) acc[i][j] = (f32x4){0.f, 0.f, 0.f, 0.f};
  int srow = lane >> 2, scol = (lane & 3) * 8;
  int fr = lane & 15, ko = (lane >> 4) * 8;
  const _Float16* Ag = A + (size_t)(m0 + srow) * Kd + scol;
  const _Float16* Bg = Bt + (size_t)(n0 + srow) * Kd + scol;

  for (int k0 = 0; k0 < Kd; k0 += 32) {
    #pragma unroll
    for (int j = 0; j < 2; j++) {
      int rb = (w * 2 + j) * 16;
      gload_lds16(Ag + (size_t)rb * Kd + k0, As + rb * 32);
      gload_lds16(Bg + (size_t)rb * Kd + k0, Bs + rb * 32);
    }
    __syncthreads();
    f16x8 af[4], bq[4];
    #pragma unroll
    for (int mi = 0; mi < 4; mi++) af[mi] = *(const f16x8*)(As + (wr * 64 + mi * 16 + fr) * 32 + ko);
    #pragma unroll
    for (int ni = 0; ni < 4; ni++) bq[ni] = *(const f16x8*)(Bs + (wc * 64 + ni * 16 + fr) * 32 + ko);
    __syncthreads();
    #pragma unroll
    for (int mi = 0; mi < 4; mi++)
      #pragma unroll
      for (int ni = 0; ni < 4; ni++)
        acc[mi][ni] = __builtin_amdgcn_mfma_f32_16x16x32_f16(af[mi], bq[ni], acc[mi][ni], 0, 0, 0);
  }
  int rbase = m0 + wr * 64 + ((lane >> 4) << 2);
  int cbase = n0 + wc * 64 + (lane & 15);
  #pragma unroll
  for (int mi = 0; mi < 4; mi++)
    #pragma unroll
    for (int ni = 0; ni < 4; ni++) {
      int cc = cbase + ni * 16;
      float bv = bias ? bias[cc] : 0.f;
      #pragma unroll
      for (int r = 0; r < 4; r++) {
        int rr = rbase + mi * 16 + r;
        float v = acc[mi][ni][r] + bv;
        if (Cf) Cf[(size_t)rr * N + cc] = v;
        if (Ch) Ch[(size_t)rr * N + cc] = (_Float16)v;
      }
    }
}

// Grouped expert kernel v2: 512 threads, 8 waves (wr 2 x wc 4), wave tile 64x32.
// XOR-swizzled t_s/h_s ([128][128] halves, byte ^= (row&7)<<4) -> bank-balanced
// ds_read_b128 / h-writes. 2 blocks/CU x 8 waves = 16 waves/CU for latency hiding.
__global__ __launch_bounds__(512, 4) void expert_kernel(
    const _Float16* __restrict__ t_h, const _Float16* __restrict__ W1t, const _Float16* __restrict__ W2t,
    const float* __restrict__ b1, const float* __restrict__ b2,
    const int* __restrict__ cnt, const int* __restrict__ lists, const float* __restrict__ tkw,
    float* __restrict__ slots) {
  int e = blockIdx.x >> 9;
  int m0 = (blockIdx.x & 511) * 128;
  int count = cnt[e * 64];
  if (m0 >= count) return;
  __shared__ _Float16 t_s[128 * 128];
  __shared__ _Float16 h_s[128 * 128];
  __shared__ int alist[128];
  __shared__ float aw[128];
  int tid = threadIdx.x, lane = tid & 63, w = tid >> 6;
  int wr = w >> 2, wc = w & 3;        // wr: 64-row half, wc: 32-col quarter
  int fr = lane & 15, g = lane >> 4;  // fragment row, k-group
  if (tid < 128) {
    int idx = m0 + tid;
    int a = (idx < count) ? lists[(size_t)e * NT + idx] : -1;
    alist[tid] = a;
    aw[tid] = (a >= 0) ? tkw[a] : 0.f;
  }
  __syncthreads();
  // gather t rows -> t_s (swizzled)
  for (int c = tid; c < 2048; c += 512) {
    int row = c >> 4, seg = c & 15;
    int a = alist[row];
    f16x8 v = {0, 0, 0, 0, 0, 0, 0, 0};
    if (a >= 0) v = *(const f16x8*)(t_h + (size_t)(a >> 1) * HD + seg * 8);
    int byte = (row * 256 + seg * 16) ^ ((row & 7) << 4);
    *(f16x8*)((char*)t_s + byte) = v;
  }
  __syncthreads();
  f32x4 acc2[4][2];
  #pragma unroll
  for (int i = 0; i < 4; i++)
    #pragma unroll
    for (int j = 0; j < 2; j++) acc2[i][j] = (f32x4){0.f, 0.f, 0.f, 0.f};

  for (int ch = 0; ch < 4; ch++) {
    // ---- W1 phase: acc1 = t_s @ W1[e][:, ch*128 + wc*32 ...] ----
    f32x4 acc1[4][2];
    #pragma unroll
    for (int i = 0; i < 4; i++)
      #pragma unroll
      for (int j = 0; j < 2; j++) acc1[i][j] = (f32x4){0.f, 0.f, 0.f, 0.f};
    const _Float16* Bg = W1t + ((size_t)e * NFF + ch * 128) * HD;
    #pragma unroll
    for (int ks = 0; ks < 4; ks++) {
      f16x8 af[4], bq[2];
      #pragma unroll
      for (int mi = 0; mi < 4; mi++) {
        int row = wr * 64 + mi * 16 + fr;
        int byte = (row * 256 + ks * 64 + g * 16) ^ ((row & 7) << 4);
        af[mi] = *(const f16x8*)((const char*)t_s + byte);
      }
      #pragma unroll
      for (int ni = 0; ni < 2; ni++)
        bq[ni] = *(const f16x8*)(Bg + (size_t)(wc * 32 + ni * 16 + fr) * HD + ks * 32 + g * 8);
      #pragma unroll
      for (int mi = 0; mi < 4; mi++)
        #pragma unroll
        for (int ni = 0; ni < 2; ni++)
          acc1[mi][ni] = __builtin_amdgcn_mfma_f32_16x16x32_f16(af[mi], bq[ni], acc1[mi][ni], 0, 0, 0);
    }
    __syncthreads();   // all waves done reading h_s from previous chunk
    // relu + bias -> h_s (swizzled)
    #pragma unroll
    for (int mi = 0; mi < 4; mi++)
      #pragma unroll
      for (int ni = 0; ni < 2; ni++) {
        int hc = wc * 32 + ni * 16 + fr;
        float bv = b1[e * NFF + ch * 128 + hc];
        #pragma unroll
        for (int r = 0; r < 4; r++) {
          int hr = wr * 64 + mi * 16 + g * 4 + r;
          int byte = (hr * 256 + hc * 2) ^ ((hr & 7) << 4);
          float v = acc1[mi][ni][r] + bv;
          *(_Float16*)((char*)h_s + byte) = (_Float16)fmaxf(v, 0.f);
        }
      }
    __syncthreads();   // h ready
    // ---- W2 phase: acc2 += h_s @ W2[e][ch*128 ...][:] ----
    const _Float16* B2 = W2t + (size_t)e * HD * NFF + (size_t)ch * 128;
    #pragma unroll
    for (int ks = 0; ks < 4; ks++) {
      f16x8 af[4], bq[2];
      #pragma unroll
      for (int mi = 0; mi < 4; mi++) {
        int row = wr * 64 + mi * 16 + fr;
        int byte = (row * 256 + ks * 64 + g * 16) ^ ((row & 7) << 4);
        af[mi] = *(const f16x8*)((const char*)h_s + byte);
      }
      #pragma unroll
      for (int ni = 0; ni < 2; ni++)
        bq[ni] = *(const f16x8*)(B2 + (size_t)(wc * 32 + ni * 16 + fr) * NFF + ks * 32 + g * 8);
      #pragma unroll
      for (int mi = 0; mi < 4; mi++)
        #pragma unroll
        for (int ni = 0; ni < 2; ni++)
          acc2[mi][ni] = __builtin_amdgcn_mfma_f32_16x16x32_f16(af[mi], bq[ni], acc2[mi][ni], 0, 0, 0);
    }
  }
  // epilogue: gate-scale + scatter to slots
  #pragma unroll
  for (int mi = 0; mi < 4; mi++)
    #pragma unroll
    for (int ni = 0; ni < 2; ni++) {
      int ncol = wc * 32 + ni * 16 + fr;
      float bv = b2[e * HD + ncol];
      #pragma unroll
      for (int r = 0; r < 4; r++) {
        int m = wr * 64 + mi * 16 + g * 4 + r;
        int a = alist[m];
        if (a >= 0) slots[(size_t)a * HD + ncol] = aw[m] * (acc2[mi][ni][r] + bv);
      }
    }
}

// combine slots -> momentum update -> residual -> LayerNorm; writes nm_out (fp32) + out_h (fp16)
// 1 wave per token (2 elems/lane), 4 tokens/block
__global__ __launch_bounds__(256) void combine_ln_kernel(
    const float* __restrict__ slots, const float* __restrict__ momentum,
    const _Float16* __restrict__ t_h, const float* __restrict__ ln_g, const float* __restrict__ ln_b,
    float* __restrict__ nm_out, _Float16* __restrict__ out_h) {
  int w = threadIdx.x >> 6, lane = threadIdx.x & 63;
  int tok = blockIdx.x * 4 + w;
  int d0 = lane * 2;
  float2 s0 = *(const float2*)(slots + (size_t)tok * 256 + d0);
  float2 s1 = *(const float2*)(slots + (size_t)tok * 256 + 128 + d0);
  float2 mo = *(const float2*)(momentum + (size_t)tok * HD + d0);
  f16x2 tv = *(const f16x2*)(t_h + (size_t)tok * HD + d0);
  float nm0 = -(s0.x + s1.x) + MU_F * mo.x;
  float nm1 = -(s0.y + s1.y) + MU_F * mo.y;
  float2 nm2; nm2.x = nm0; nm2.y = nm1;
  *(float2*)(nm_out + (size_t)tok * HD + d0) = nm2;
  float r0 = (float)tv.x + nm0;
  float r1 = (float)tv.y + nm1;
  float s = r0 + r1, sq = r0 * r0 + r1 * r1;
  #pragma unroll
  for (int m = 1; m < 64; m <<= 1) { s += __shfl_xor(s, m, 64); sq += __shfl_xor(sq, m, 64); }
  float mean = s * (1.f / 128.f);
  float var = sq * (1.f / 128.f) - mean * mean;
  float is = rsqrtf(var + LN_EPS_F);
  float y0 = (r0 - mean) * is * ln_g[d0] + ln_b[d0];
  float y1 = (r1 - mean) * is * ln_g[d0 + 1] + ln_b[d0 + 1];
  f16x2 yo = { (_Float16)y0, (_Float16)y1 };
  *(f16x2*)(out_h + (size_t)tok * HD + d0) = yo;
}

extern "C" void kernel_launch(void* const* d_in, const int* in_sizes, int n_in,
                              void* d_out, int out_size, void* d_ws, size_t ws_size,
                              hipStream_t stream) {
  const float* x        = (const float*)d_in[0];
  const float* momentum = (const float*)d_in[1];
  const float* split_W  = (const float*)d_in[2];
  const float* split_b  = (const float*)d_in[3];
  const float* gate_W   = (const float*)d_in[4];
  const float* gate_b   = (const float*)d_in[5];
  const float* W1       = (const float*)d_in[6];
  const float* b1       = (const float*)d_in[7];
  const float* W2       = (const float*)d_in[8];
  const float* b2       = (const float*)d_in[9];
  const float* ln_g     = (const float*)d_in[10];
  const float* ln_b     = (const float*)d_in[11];
  const float* merge_W  = (const float*)d_in[12];
  const float* merge_b  = (const float*)d_in[13];
  float* final_out = (float*)d_out;
  float* nm_out    = final_out + (size_t)NBS * ND;

  char* ws = (char*)d_ws;
  size_t off = 0;
  auto alloc = [&](size_t bytes) { void* p = ws + off; off = (off + bytes + 255) & ~(size_t)255; return p; };
  _Float16* x_h   = (_Float16*)alloc((size_t)NBS * ND * 2);
  _Float16* t_h   = (_Float16*)alloc((size_t)NT * HD * 2);
  _Float16* out_h = (_Float16*)alloc((size_t)NT * HD * 2);
  _Float16* sWt   = (_Float16*)alloc((size_t)ND * ND * 2);
  _Float16* mWt   = (_Float16*)alloc((size_t)ND * ND * 2);
  _Float16* W1t   = (_Float16*)alloc((size_t)NE * HD * NFF * 2);
  _Float16* W2t   = (_Float16*)alloc((size_t)NE * HD * NFF * 2);
  double*   G     = (double*)alloc((size_t)ND * 64 * 8);
  double*   gbias = (double*)alloc(64 * 8);
  float*    tkw   = (float*)alloc((size_t)NT * 2 * 4);
  int*      lists = (int*)alloc((size_t)NE * NT * 4);
  int*      cnt   = (int*)alloc(512 * 4);
  float*    slots = (float*)alloc((size_t)NT * 2 * HD * 4);
  (void)in_sizes; (void)n_in; (void)out_size; (void)ws_size;

  zero_cnt_kernel<<<1, 512, 0, stream>>>(cnt);
  cvt_f16_kernel<<<(NBS * ND / 4 + 255) / 256, 256, 0, stream>>>(x, x_h, NBS * ND / 4);
  tr_cvt_kernel<<<dim3(32, 32, 1), dim3(32, 8), 0, stream>>>(split_W, sWt, ND, ND);
  tr_cvt_kernel<<<dim3(32, 32, 1), dim3(32, 8), 0, stream>>>(merge_W, mWt, ND, ND);
  tr_cvt_kernel<<<dim3(16, 4, 8), dim3(32, 8), 0, stream>>>(W1, W1t, HD, NFF);
  tr_cvt_kernel<<<dim3(4, 16, 8), dim3(32, 8), 0, stream>>>(W2, W2t, NFF, HD);
  build_G_kernel<<<256, 256, 0, stream>>>(split_W, split_b, gate_W, gate_b, G, gbias);
  // t = x @ split_W + split_b   (fp16 out for downstream MFMA)
  gemm_f16_kernel<<<dim3(8, 64), 256, 0, stream>>>(x_h, sWt, split_b, nullptr, t_h, NBS, ND, ND);
  gate_kernel<<<512, 256, 0, stream>>>(x, G, gbias, tkw, lists, cnt);
  expert_kernel<<<NE * 512, 512, 0, stream>>>(t_h, W1t, W2t, b1, b2, cnt, lists, tkw, slots);
  combine_ln_kernel<<<NT / 4, 256, 0, stream>>>(slots, momentum, t_h, ln_g, ln_b, nm_out, out_h);
  // final = out @ merge_W + merge_b
  gemm_f16_kernel<<<dim3(8, 64), 256, 0, stream>>>(out_h, mWt, merge_b, final_out, nullptr, NBS, ND, ND);
}

// Round 6
// 270.229 us; speedup vs baseline: 1.2361x; 1.2361x over previous
//
#include <hip/hip_runtime.h>

#define NBATCH 4
#define NS 2048
#define ND 1024
#define NH 8
#define HD 128
#define NFF 512
#define NE 8
#define NT 65536       /* B*S*H tokens */
#define NBS 8192       /* B*S rows */
#define MU_F 0.7f
#define LN_EPS_F 1e-5f

typedef __attribute__((ext_vector_type(4))) float f32x4;
typedef __attribute__((ext_vector_type(2))) double f64x2;
typedef __attribute__((ext_vector_type(8))) _Float16 f16x8;
typedef __attribute__((ext_vector_type(4))) _Float16 f16x4;
typedef __attribute__((ext_vector_type(2))) _Float16 f16x2;

__device__ __forceinline__ void gload_lds16(const void* g, void* l) {
  __builtin_amdgcn_global_load_lds(
      (const __attribute__((address_space(1))) unsigned int*)g,
      (__attribute__((address_space(3))) unsigned int*)l, 16, 0, 0);
}

// cnt is strided: cnt[e*64] so the 8 counters live in different cache lines/TCC channels
__global__ void zero_cnt_kernel(int* cnt) {
  cnt[threadIdx.x] = 0;
}

// plain fp32 -> fp16 convert, 4 elems/thread
__global__ void cvt_f16_kernel(const float* __restrict__ in, _Float16* __restrict__ out, int n4) {
  int i = blockIdx.x * blockDim.x + threadIdx.x;
  if (i >= n4) return;
  float4 v = ((const float4*)in)[i];
  f16x4 h = { (_Float16)v.x, (_Float16)v.y, (_Float16)v.z, (_Float16)v.w };
  *(f16x4*)(out + (size_t)i * 4) = h;
}

// batched transpose + convert: in [batch][R][C] f32 -> out [batch][C][R] f16
// R, C multiples of 32. block (32,8), grid (C/32, R/32, batch)
__global__ void tr_cvt_kernel(const float* __restrict__ in, _Float16* __restrict__ out, int R, int C) {
  __shared__ float tile[32][33];
  int b = blockIdx.z;
  const float* inp = in + (size_t)b * R * C;
  _Float16* outp = out + (size_t)b * R * C;
  int c = blockIdx.x * 32 + threadIdx.x;
  int r0 = blockIdx.y * 32;
  #pragma unroll
  for (int i = 0; i < 4; i++) {
    int r = r0 + threadIdx.y + i * 8;
    tile[threadIdx.y + i * 8][threadIdx.x] = inp[(size_t)r * C + c];
  }
  __syncthreads();
  int rr = r0 + threadIdx.x;
  #pragma unroll
  for (int i = 0; i < 4; i++) {
    int cc = blockIdx.x * 32 + threadIdx.y + i * 8;
    outp[(size_t)cc * R + rr] = (_Float16)tile[threadIdx.x][threadIdx.y + i * 8];
  }
}

// G[d][o] (o = h*8+e) = sum_j split_W[d][h*128+j] * gate_W[j][e]  (fp64)
// gbias[o] = split_b[h*128:] . gate_W[:,e] + gate_b[e]
__global__ void build_G_kernel(const float* __restrict__ split_W, const float* __restrict__ split_b,
                               const float* __restrict__ gate_W, const float* __restrict__ gate_b,
                               double* __restrict__ G, double* __restrict__ gbias) {
  int idx = blockIdx.x * 256 + threadIdx.x;   // 65536 total
  int d = idx >> 6, o = idx & 63, h = o >> 3, e = o & 7;
  double acc = 0.0;
  for (int j = 0; j < 128; j++)
    acc += (double)split_W[(size_t)d * ND + h * 128 + j] * (double)gate_W[j * 8 + e];
  G[idx] = acc;
  if (idx < 64) {
    double bacc = 0.0;
    for (int j = 0; j < 128; j++)
      bacc += (double)split_b[h * 128 + j] * (double)gate_W[j * 8 + e];
    gbias[idx] = bacc + (double)gate_b[e];
  }
}

// fp64 logits = x @ G + gbias, top-2 per (row,h), softmax, per-expert lists.
// v4: LDS fp64 mini-GEMM (conflict-free Gsx[kp][col] f64x2 layout) +
// hierarchical atomics (LDS counts -> 8 strided global atomics/block).
__global__ __launch_bounds__(256) void gate_kernel(const float* __restrict__ x,
    const double* __restrict__ G, const double* __restrict__ gbias,
    float* __restrict__ tkw, int* __restrict__ lists, int* __restrict__ cnt) {
  __shared__ f64x2 Gsx[32 * 64];     // 32 KB, [kp][col]
  __shared__ double xsd[16][66];     // 8.25 KB
  __shared__ double lg[16 * 64];     // 8 KB
  __shared__ int lcnt[8];
  __shared__ int lbase[8];
  int tid = threadIdx.x, lane = tid & 63, w = tid >> 6;
  int bs0 = blockIdx.x * 16;
  double acc[4];
  #pragma unroll
  for (int r = 0; r < 4; r++) acc[r] = 0.0;
  int xrow = tid >> 4, xc4 = tid & 15;
  const double* xr = &xsd[0][0] + (w * 4) * 66;
  if (tid < 8) lcnt[tid] = 0;

  for (int ch = 0; ch < 16; ch++) {
    __syncthreads();           // previous chunk's reads complete before overwrite
    float4 xv4 = *(const float4*)(x + (size_t)(bs0 + xrow) * ND + ch * 64 + xc4 * 4);
    f64x2 xa = { (double)xv4.x, (double)xv4.y };
    f64x2 xb = { (double)xv4.z, (double)xv4.w };
    *(f64x2*)&xsd[xrow][xc4 * 4]     = xa;
    *(f64x2*)&xsd[xrow][xc4 * 4 + 2] = xb;
    #pragma unroll
    for (int i = 0; i < 8; i++) {
      int idx = i * 256 + tid, kp = idx >> 6, c = idx & 63;
      const double* gp = G + (size_t)(ch * 64 + kp * 2) * 64 + c;
      f64x2 gv = { gp[0], gp[64] };
      Gsx[idx] = gv;
    }
    __syncthreads();
    #pragma unroll 4
    for (int kp = 0; kp < 32; kp++) {
      f64x2 g = Gsx[kp * 64 + lane];       // contiguous 16B/lane: conflict-free
      #pragma unroll
      for (int r = 0; r < 4; r++) {
        f64x2 xv = *(const f64x2*)(xr + r * 66 + kp * 2);   // broadcast
        acc[r] += xv.x * g.x;
        acc[r] += xv.y * g.y;
      }
    }
  }
  double gb = gbias[lane];
  #pragma unroll
  for (int r = 0; r < 4; r++)
    lg[(w * 4 + r) * 64 + lane] = acc[r] + gb;
  __syncthreads();

  int i1 = 0, i2 = 0, token = 0, p1 = 0, p2 = 0;
  if (tid < 128) {
    int row = tid >> 3, h = tid & 7;
    const double* L = lg + row * 64 + h * 8;
    double v1 = L[0];
    #pragma unroll
    for (int e2 = 1; e2 < 8; e2++) if (L[e2] > v1) { v1 = L[e2]; i1 = e2; }
    i2 = -1; double v2 = -1e300;
    #pragma unroll
    for (int e2 = 0; e2 < 8; e2++) if (e2 != i1 && L[e2] > v2) { v2 = L[e2]; i2 = e2; }
    float ex = expf((float)(v2 - v1));        // <= 1
    float den = 1.f + ex;
    float g1 = 1.f / den, g2 = ex / den;
    token = (bs0 + row) * 8 + h;
    tkw[token * 2]     = g1;
    tkw[token * 2 + 1] = g2;
    p1 = atomicAdd(&lcnt[i1], 1);             // LDS atomics: cheap
    p2 = atomicAdd(&lcnt[i2], 1);
  }
  __syncthreads();
  if (tid < 8) lbase[tid] = atomicAdd(cnt + tid * 64, lcnt[tid]);   // 8 global atomics/block
  __syncthreads();
  if (tid < 128) {
    lists[(size_t)i1 * NT + lbase[i1] + p1] = token * 2;
    lists[(size_t)i2 * NT + lbase[i2] + p2] = token * 2 + 1;
  }
}

// C[M][N] = A[M][K] @ Bt[N][K]^T + bias; fp16 inputs, fp32 acc.
// 128x128 tile, BK=32, 4 waves (2x2 of 64x64), global_load_lds width 16.
__global__ __launch_bounds__(256) void gemm_f16_kernel(
    const _Float16* __restrict__ A, const _Float16* __restrict__ Bt,
    const float* __restrict__ bias, float* __restrict__ Cf, _Float16* __restrict__ Ch,
    int M, int N, int Kd) {
  __shared__ _Float16 As[128 * 32];
  __shared__ _Float16 Bs[128 * 32];
  int tid = threadIdx.x, lane = tid & 63, w = tid >> 6;
  int wr = w >> 1, wc = w & 1;
  int m0 = blockIdx.y * 128, n0 = blockIdx.x * 128;
  f32x4 acc[4][4];
  #pragma unroll
  for (int i = 0; i < 4; i++)
    #pragma unroll
    for (int j = 0; j < 4; j++) acc[i][j] = (f32x4){0.f, 0.f, 0.f, 0.f};
  int srow = lane >> 2, scol = (lane & 3) * 8;
  int fr = lane & 15, ko = (lane >> 4) * 8;
  const _Float16* Ag = A + (size_t)(m0 + srow) * Kd + scol;
  const _Float16* Bg = Bt + (size_t)(n0 + srow) * Kd + scol;

  for (int k0 = 0; k0 < Kd; k0 += 32) {
    #pragma unroll
    for (int j = 0; j < 2; j++) {
      int rb = (w * 2 + j) * 16;
      gload_lds16(Ag + (size_t)rb * Kd + k0, As + rb * 32);
      gload_lds16(Bg + (size_t)rb * Kd + k0, Bs + rb * 32);
    }
    __syncthreads();
    f16x8 af[4], bq[4];
    #pragma unroll
    for (int mi = 0; mi < 4; mi++) af[mi] = *(const f16x8*)(As + (wr * 64 + mi * 16 + fr) * 32 + ko);
    #pragma unroll
    for (int ni = 0; ni < 4; ni++) bq[ni] = *(const f16x8*)(Bs + (wc * 64 + ni * 16 + fr) * 32 + ko);
    __syncthreads();
    #pragma unroll
    for (int mi = 0; mi < 4; mi++)
      #pragma unroll
      for (int ni = 0; ni < 4; ni++)
        acc[mi][ni] = __builtin_amdgcn_mfma_f32_16x16x32_f16(af[mi], bq[ni], acc[mi][ni], 0, 0, 0);
  }
  int rbase = m0 + wr * 64 + ((lane >> 4) << 2);
  int cbase = n0 + wc * 64 + (lane & 15);
  #pragma unroll
  for (int mi = 0; mi < 4; mi++)
    #pragma unroll
    for (int ni = 0; ni < 4; ni++) {
      int cc = cbase + ni * 16;
      float bv = bias ? bias[cc] : 0.f;
      #pragma unroll
      for (int r = 0; r < 4; r++) {
        int rr = rbase + mi * 16 + r;
        float v = acc[mi][ni][r] + bv;
        if (Cf) Cf[(size_t)rr * N + cc] = v;
        if (Ch) Ch[(size_t)rr * N + cc] = (_Float16)v;
      }
    }
}

// Grouped expert kernel v3: weights staged in LDS (double-buffered global_load_lds
// with pre-swizzled source, rule #21), t-fragments held in REGISTERS across all
// phases, XOR-swizzled h_s, XCD-aware expert mapping (e = blockIdx&7), fp16 slots.
// 512 thr (8 waves, 2x4), tile 128 tokens; per phase: issue next W chunk, MFMA
// from LDS, vmcnt(0)+barrier (minimal 2-phase pipeline, guide T3).
__global__ __launch_bounds__(512, 2) void expert_kernel(
    const _Float16* __restrict__ t_h, const _Float16* __restrict__ W1t, const _Float16* __restrict__ W2t,
    const float* __restrict__ b1, const float* __restrict__ b2,
    const int* __restrict__ cnt, const int* __restrict__ lists, const float* __restrict__ tkw,
    _Float16* __restrict__ slots) {
  int e = blockIdx.x & 7;              // consecutive blocks -> different XCDs; expert e pinned to XCD e%8
  int m0 = (blockIdx.x >> 3) * 128;
  int count = cnt[e * 64];
  if (m0 >= count) return;
  __shared__ _Float16 Wb[2][128 * 128];   // 2 x 32 KB weight chunks (swizzled layout)
  __shared__ _Float16 h_s[128 * 128];     // 32 KB, swizzled
  __shared__ int alist[128];
  __shared__ float aw[128];
  int tid = threadIdx.x, lane = tid & 63, w = tid >> 6;
  int wr = w >> 2, wc = w & 3;          // 2 x 4 wave grid: 64-row half x 32-col quarter
  int fr = lane & 15, g = lane >> 4;

  if (tid < 128) {
    int idx = m0 + tid;
    int a = (idx < count) ? lists[(size_t)e * NT + idx] : -1;
    alist[tid] = a;
    aw[tid] = (a >= 0) ? tkw[a] : 0.f;
  }
  __syncthreads();

  // issue weight chunk p (p=2*ch+isW2) into Wb[b]; LDS linear dest, source
  // pre-swizzled so read-side XOR ((r&7) on 16B chunks) sees the right data.
  auto issue = [&](int p, int b) {
    int ch = p >> 1;
    const _Float16* base = (p & 1) ? (W2t + (size_t)e * (HD * NFF))
                                   : (W1t + (size_t)e * (NFF * HD));
    #pragma unroll
    for (int j = 0; j < 4; j++) {
      int n = j * 512 + tid;               // 0..2047 16B-chunks
      int r = n >> 4, c2 = n & 15, c = c2 ^ (r & 7);
      const _Float16* src = (p & 1)
          ? base + (size_t)r * NFF + ch * 128 + c * 8      // W2: [d=128][ff 512], chunk cols ff
          : base + (size_t)(ch * 128 + r) * HD + c * 8;    // W1: [ff 512][k=128], chunk rows ff
      gload_lds16(src, (_Float16*)&Wb[b][0] + n * 8);
    }
  };

  issue(0, 0);
  // gather this wave's token rows into registers (held across all phases)
  f16x8 af[4][4];
  #pragma unroll
  for (int mi = 0; mi < 4; mi++) {
    int rloc = wr * 64 + mi * 16 + fr;
    int a = alist[rloc];
    const _Float16* tb = t_h + (size_t)(a >> 1) * HD;
    #pragma unroll
    for (int ks = 0; ks < 4; ks++) {
      f16x8 v = {0, 0, 0, 0, 0, 0, 0, 0};
      if (a >= 0) v = *(const f16x8*)(tb + ks * 32 + g * 8);
      af[mi][ks] = v;
    }
  }
  // hoist biases
  float b1v[4][2], b2v[2];
  #pragma unroll
  for (int ch = 0; ch < 4; ch++)
    #pragma unroll
    for (int ni = 0; ni < 2; ni++)
      b1v[ch][ni] = b1[e * NFF + ch * 128 + wc * 32 + ni * 16 + fr];
  #pragma unroll
  for (int ni = 0; ni < 2; ni++)
    b2v[ni] = b2[e * HD + wc * 32 + ni * 16 + fr];

  asm volatile("s_waitcnt vmcnt(0)");
  __syncthreads();                       // chunk0 + af ready

  f32x4 acc2[4][2];
  #pragma unroll
  for (int i = 0; i < 4; i++)
    #pragma unroll
    for (int j = 0; j < 2; j++) acc2[i][j] = (f32x4){0.f, 0.f, 0.f, 0.f};

  for (int ch = 0; ch < 4; ch++) {
    int p = ch * 2;
    // ---- W1 phase: acc1 = t @ W1chunk (reads Wb[p&1]) ----
    if (p + 1 < 8) issue(p + 1, (p + 1) & 1);
    f32x4 acc1[4][2];
    #pragma unroll
    for (int i = 0; i < 4; i++)
      #pragma unroll
      for (int j = 0; j < 2; j++) acc1[i][j] = (f32x4){0.f, 0.f, 0.f, 0.f};
    {
      const char* WB = (const char*)&Wb[p & 1][0];
      #pragma unroll
      for (int ks = 0; ks < 4; ks++) {
        f16x8 bq[2];
        #pragma unroll
        for (int ni = 0; ni < 2; ni++) {
          int rw = wc * 32 + ni * 16 + fr;
          int byte = rw * 256 + ((ks * 64 + g * 16) ^ ((rw & 7) << 4));
          bq[ni] = *(const f16x8*)(WB + byte);
        }
        #pragma unroll
        for (int mi = 0; mi < 4; mi++)
          #pragma unroll
          for (int ni = 0; ni < 2; ni++)
            acc1[mi][ni] = __builtin_amdgcn_mfma_f32_16x16x32_f16(af[mi][ks], bq[ni], acc1[mi][ni], 0, 0, 0);
      }
    }
    // relu + bias -> h_s (swizzled); prev phase's h_s readers finished at last barrier
    #pragma unroll
    for (int mi = 0; mi < 4; mi++)
      #pragma unroll
      for (int ni = 0; ni < 2; ni++) {
        int hc = wc * 32 + ni * 16 + fr;
        #pragma unroll
        for (int r = 0; r < 4; r++) {
          int hr = wr * 64 + mi * 16 + g * 4 + r;
          int byte = hr * 256 + ((hc * 2) ^ ((hr & 7) << 4));
          float v = acc1[mi][ni][r] + b1v[ch][ni];
          *(_Float16*)((char*)h_s + byte) = (_Float16)fmaxf(v, 0.f);
        }
      }
    asm volatile("s_waitcnt vmcnt(0)");
    __syncthreads();                     // h_s ready + W2 chunk ready
    // ---- W2 phase: acc2 += h @ W2chunk (reads Wb[(p+1)&1]) ----
    if (p + 2 < 8) issue(p + 2, (p + 2) & 1);   // next ch's W1 into just-freed buffer
    {
      const char* WB = (const char*)&Wb[(p + 1) & 1][0];
      #pragma unroll
      for (int ks = 0; ks < 4; ks++) {
        f16x8 ah[4], bq[2];
        #pragma unroll
        for (int mi = 0; mi < 4; mi++) {
          int row = wr * 64 + mi * 16 + fr;
          int byte = row * 256 + ((ks * 64 + g * 16) ^ ((row & 7) << 4));
          ah[mi] = *(const f16x8*)((const char*)h_s + byte);
        }
        #pragma unroll
        for (int ni = 0; ni < 2; ni++) {
          int rw = wc * 32 + ni * 16 + fr;
          int byte = rw * 256 + ((ks * 64 + g * 16) ^ ((rw & 7) << 4));
          bq[ni] = *(const f16x8*)(WB + byte);
        }
        #pragma unroll
        for (int mi = 0; mi < 4; mi++)
          #pragma unroll
          for (int ni = 0; ni < 2; ni++)
            acc2[mi][ni] = __builtin_amdgcn_mfma_f32_16x16x32_f16(ah[mi], bq[ni], acc2[mi][ni], 0, 0, 0);
      }
    }
    asm volatile("s_waitcnt vmcnt(0)");
    __syncthreads();                     // next W1 chunk ready; h_s reads done
  }
  // epilogue: gate-scale + fp16 scatter to slots
  #pragma unroll
  for (int mi = 0; mi < 4; mi++)
    #pragma unroll
    for (int ni = 0; ni < 2; ni++) {
      int ncol = wc * 32 + ni * 16 + fr;
      #pragma unroll
      for (int r = 0; r < 4; r++) {
        int m = wr * 64 + mi * 16 + g * 4 + r;
        int a = alist[m];
        if (a >= 0)
          slots[(size_t)a * HD + ncol] = (_Float16)(aw[m] * (acc2[mi][ni][r] + b2v[ni]));
      }
    }
}

// combine slots -> momentum update -> residual -> LayerNorm; writes nm_out (fp32) + out_h (fp16)
// 1 wave per token (2 elems/lane), 4 tokens/block
__global__ __launch_bounds__(256) void combine_ln_kernel(
    const _Float16* __restrict__ slots, const float* __restrict__ momentum,
    const _Float16* __restrict__ t_h, const float* __restrict__ ln_g, const float* __restrict__ ln_b,
    float* __restrict__ nm_out, _Float16* __restrict__ out_h) {
  int w = threadIdx.x >> 6, lane = threadIdx.x & 63;
  int tok = blockIdx.x * 4 + w;
  int d0 = lane * 2;
  f16x2 s0 = *(const f16x2*)(slots + (size_t)tok * 256 + d0);
  f16x2 s1 = *(const f16x2*)(slots + (size_t)tok * 256 + 128 + d0);
  float2 mo = *(const float2*)(momentum + (size_t)tok * HD + d0);
  f16x2 tv = *(const f16x2*)(t_h + (size_t)tok * HD + d0);
  float nm0 = -((float)s0.x + (float)s1.x) + MU_F * mo.x;
  float nm1 = -((float)s0.y + (float)s1.y) + MU_F * mo.y;
  float2 nm2; nm2.x = nm0; nm2.y = nm1;
  *(float2*)(nm_out + (size_t)tok * HD + d0) = nm2;
  float r0 = (float)tv.x + nm0;
  float r1 = (float)tv.y + nm1;
  float s = r0 + r1, sq = r0 * r0 + r1 * r1;
  #pragma unroll
  for (int m = 1; m < 64; m <<= 1) { s += __shfl_xor(s, m, 64); sq += __shfl_xor(sq, m, 64); }
  float mean = s * (1.f / 128.f);
  float var = sq * (1.f / 128.f) - mean * mean;
  float is = rsqrtf(var + LN_EPS_F);
  float y0 = (r0 - mean) * is * ln_g[d0] + ln_b[d0];
  float y1 = (r1 - mean) * is * ln_g[d0 + 1] + ln_b[d0 + 1];
  f16x2 yo = { (_Float16)y0, (_Float16)y1 };
  *(f16x2*)(out_h + (size_t)tok * HD + d0) = yo;
}

extern "C" void kernel_launch(void* const* d_in, const int* in_sizes, int n_in,
                              void* d_out, int out_size, void* d_ws, size_t ws_size,
                              hipStream_t stream) {
  const float* x        = (const float*)d_in[0];
  const float* momentum = (const float*)d_in[1];
  const float* split_W  = (const float*)d_in[2];
  const float* split_b  = (const float*)d_in[3];
  const float* gate_W   = (const float*)d_in[4];
  const float* gate_b   = (const float*)d_in[5];
  const float* W1       = (const float*)d_in[6];
  const float* b1       = (const float*)d_in[7];
  const float* W2       = (const float*)d_in[8];
  const float* b2       = (const float*)d_in[9];
  const float* ln_g     = (const float*)d_in[10];
  const float* ln_b     = (const float*)d_in[11];
  const float* merge_W  = (const float*)d_in[12];
  const float* merge_b  = (const float*)d_in[13];
  float* final_out = (float*)d_out;
  float* nm_out    = final_out + (size_t)NBS * ND;

  char* ws = (char*)d_ws;
  size_t off = 0;
  auto alloc = [&](size_t bytes) { void* p = ws + off; off = (off + bytes + 255) & ~(size_t)255; return p; };
  _Float16* x_h   = (_Float16*)alloc((size_t)NBS * ND * 2);
  _Float16* t_h   = (_Float16*)alloc((size_t)NT * HD * 2);
  _Float16* out_h = (_Float16*)alloc((size_t)NT * HD * 2);
  _Float16* sWt   = (_Float16*)alloc((size_t)ND * ND * 2);
  _Float16* mWt   = (_Float16*)alloc((size_t)ND * ND * 2);
  _Float16* W1t   = (_Float16*)alloc((size_t)NE * HD * NFF * 2);
  _Float16* W2t   = (_Float16*)alloc((size_t)NE * HD * NFF * 2);
  double*   G     = (double*)alloc((size_t)ND * 64 * 8);
  double*   gbias = (double*)alloc(64 * 8);
  float*    tkw   = (float*)alloc((size_t)NT * 2 * 4);
  int*      lists = (int*)alloc((size_t)NE * NT * 4);
  int*      cnt   = (int*)alloc(512 * 4);
  _Float16* slots = (_Float16*)alloc((size_t)NT * 2 * HD * 2);
  (void)in_sizes; (void)n_in; (void)out_size; (void)ws_size;

  zero_cnt_kernel<<<1, 512, 0, stream>>>(cnt);
  cvt_f16_kernel<<<(NBS * ND / 4 + 255) / 256, 256, 0, stream>>>(x, x_h, NBS * ND / 4);
  tr_cvt_kernel<<<dim3(32, 32, 1), dim3(32, 8), 0, stream>>>(split_W, sWt, ND, ND);
  tr_cvt_kernel<<<dim3(32, 32, 1), dim3(32, 8), 0, stream>>>(merge_W, mWt, ND, ND);
  tr_cvt_kernel<<<dim3(16, 4, 8), dim3(32, 8), 0, stream>>>(W1, W1t, HD, NFF);
  tr_cvt_kernel<<<dim3(4, 16, 8), dim3(32, 8), 0, stream>>>(W2, W2t, NFF, HD);
  build_G_kernel<<<256, 256, 0, stream>>>(split_W, split_b, gate_W, gate_b, G, gbias);
  // t = x @ split_W + split_b   (fp16 out for downstream MFMA)
  gemm_f16_kernel<<<dim3(8, 64), 256, 0, stream>>>(x_h, sWt, split_b, nullptr, t_h, NBS, ND, ND);
  gate_kernel<<<512, 256, 0, stream>>>(x, G, gbias, tkw, lists, cnt);
  expert_kernel<<<NE * 512, 512, 0, stream>>>(t_h, W1t, W2t, b1, b2, cnt, lists, tkw, slots);
  combine_ln_kernel<<<NT / 4, 256, 0, stream>>>(slots, momentum, t_h, ln_g, ln_b, nm_out, out_h);
  // final = out @ merge_W + merge_b
  gemm_f16_kernel<<<dim3(8, 64), 256, 0, stream>>>(out_h, mWt, merge_b, final_out, nullptr, NBS, ND, ND);
}